// Round 5
// baseline (1165.301 us; speedup 1.0000x reference)
//
#include <hip/hip_runtime.h>
#include <math.h>

#define BB 4
#define LSEQ 2048
#define DMODEL 128
#define DINNER 256
#define DSTATE 16
#define NLAYERS 8
#define NCH 256    // number of time chunks
#define LCH 8      // chunk length
#define HALO 3
#define ROWS 11    // LCH + HALO
#define PROWS 12   // padded rows (4 pos-groups x 3)
#define CB 16      // combine prefetch batch

__device__ __forceinline__ float silu_f(float x) {
    return x / (1.0f + __expf(-x));
}
__device__ __forceinline__ float softplus_f(float x) {
    return (x > 20.0f) ? x : log1pf(__expf(x));
}
__device__ __forceinline__ float dot4(float4 a, float4 b) {
    return a.x*b.x + a.y*b.y + a.z*b.z + a.w*b.w;
}

// ---------------- stem ----------------------------------------------------
__global__ __launch_bounds__(256)
void k_stem(const float* __restrict__ x, const float* __restrict__ sw,
            const float* __restrict__ sb, float* __restrict__ h)
{
    int i = blockIdx.x * 256 + threadIdx.x;
    if (i >= BB * LSEQ * DMODEL) return;
    int m = i & (DMODEL - 1);
    int bl = i >> 7;
    const float* xf = x + bl * 4;
    float4 w = *(const float4*)(sw + m * 4);
    h[i] = sb[m] + xf[0]*w.x + xf[1]*w.y + xf[2]*w.z + xf[3]*w.w;
}

// ---------------- K_A: LN+in_proj+conv+silu+x_proj+dt+softplus+local scan -
// grid (NCH, BB), 256 threads, 4+ blocks/CU.
__global__ __launch_bounds__(256, 4)
void k_layer_a(const float* __restrict__ h, const float* __restrict__ g,
               const float* __restrict__ bln, const float* __restrict__ W,
               const float* __restrict__ cw, const float* __restrict__ cb,
               const float* __restrict__ xw, const float* __restrict__ dw,
               const float* __restrict__ db, const float* __restrict__ A_log,
               const float* __restrict__ Dv,
               float* __restrict__ z, float* __restrict__ delta_out,
               float* __restrict__ Cm, float* __restrict__ y,
               float* __restrict__ P, float* __restrict__ hF)
{
    __shared__ float xn[PROWS][132];   // normalized input rows (pos t0-3..t0+7, +pad)
    __shared__ float xp[PROWS][260];   // in_proj xp; rows 0..7 become xs after conv
    __shared__ float dbl[LCH][40];     // x_proj outputs: 0..7 dt, 8..23 B, 24..39 C
    int c = blockIdx.x, b = blockIdx.y;
    int t0 = c * LCH;
    int pos0 = b * LSEQ + t0;
    int t = threadIdx.x;

    // stage input rows (halo rows with l<0 and pad row 11 are zero)
    for (int j = t; j < PROWS * DMODEL; j += 256) {
        int r = j >> 7, col = j & 127;
        int l = t0 - HALO + r;
        xn[r][col] = (l < 0 || r >= ROWS) ? 0.f
                   : h[(size_t)(b * LSEQ + l) * DMODEL + col];
    }
    __syncthreads();

    // LayerNorm in place: 8 lanes per row (zero halo rows stay zero)
    {
        int r = t >> 3, lane = t & 7;
        if (r < ROWS && (t0 - HALO + r) >= 0) {
            float s = 0.f;
            #pragma unroll
            for (int k = lane; k < DMODEL; k += 8) s += xn[r][k];
            #pragma unroll
            for (int off = 4; off > 0; off >>= 1) s += __shfl_xor(s, off, 8);
            float mu = s * (1.f / DMODEL);
            float vs = 0.f;
            #pragma unroll
            for (int k = lane; k < DMODEL; k += 8) { float dv = xn[r][k] - mu; vs += dv * dv; }
            #pragma unroll
            for (int off = 4; off > 0; off >>= 1) vs += __shfl_xor(vs, off, 8);
            float rstd = rsqrtf(vs * (1.f / DMODEL) + 1e-5f);
            #pragma unroll
            for (int k = lane; k < DMODEL; k += 8)
                xn[r][k] = (xn[r][k] - mu) * rstd * g[k] + bln[k];
        }
    }
    __syncthreads();

    // in_proj: thread = (og = t>>2 owns 8 W rows, pg = t&3 owns 3 positions)
    {
        int og = t >> 2, pg = t & 3;
        const float* Wb = W + (size_t)og * 8 * DMODEL;
        float acc[8][3];
        #pragma unroll
        for (int j = 0; j < 8; j++)
            #pragma unroll
            for (int i = 0; i < 3; i++) acc[j][i] = 0.f;
        #pragma unroll 2
        for (int k4 = 0; k4 < DMODEL / 4; k4++) {
            float4 xv[3];
            #pragma unroll
            for (int i = 0; i < 3; i++)
                xv[i] = *(const float4*)&xn[pg * 3 + i][k4 * 4];
            #pragma unroll
            for (int j = 0; j < 8; j++) {
                float4 wv = *(const float4*)(Wb + j * DMODEL + k4 * 4);
                #pragma unroll
                for (int i = 0; i < 3; i++)
                    acc[j][i] += dot4(wv, xv[i]);
            }
        }
        if (og < 32) {      // rows 0..255 -> xp (positions 0..10)
            #pragma unroll
            for (int i = 0; i < 3; i++) {
                int p = pg * 3 + i;
                if (p < ROWS) {
                    *(float4*)&xp[p][og * 8]     = make_float4(acc[0][i], acc[1][i], acc[2][i], acc[3][i]);
                    *(float4*)&xp[p][og * 8 + 4] = make_float4(acc[4][i], acc[5][i], acc[6][i], acc[7][i]);
                }
            }
        } else {            // rows 256..511 -> z (positions 3..10 -> 0..7)
            int ch = (og - 32) * 8;
            #pragma unroll
            for (int i = 0; i < 3; i++) {
                int p = pg * 3 + i;
                if (p >= HALO && p < ROWS) {
                    float* dst = z + (size_t)(pos0 + p - HALO) * DINNER + ch;
                    *(float4*)dst       = make_float4(acc[0][i], acc[1][i], acc[2][i], acc[3][i]);
                    *(float4*)(dst + 4) = make_float4(acc[4][i], acc[5][i], acc[6][i], acc[7][i]);
                }
            }
        }
    }
    __syncthreads();

    // causal conv + silu, in place (column-private)
    {
        int d = t;
        float4 cwv = *(const float4*)(cw + d * 4);
        float cbv = cb[d];
        float q0 = xp[0][d], q1 = xp[1][d], q2 = xp[2][d];
        #pragma unroll
        for (int p = 0; p < LCH; p++) {
            float cur = xp[p + HALO][d];
            float xc = cbv + q0*cwv.x + q1*cwv.y + q2*cwv.z + cur*cwv.w;
            xp[p][d] = silu_f(xc);
            q0 = q1; q1 = q2; q2 = cur;
        }
    }
    __syncthreads();

    // x_proj from L2 (8-lane broadcast): og in 0..31 -> out og; og<8 also og+32
    {
        int p = t & 7, og = t >> 3;
        const float* w0 = xw + (size_t)og * DINNER;
        const float* w2 = xw + (size_t)(og + 32) * DINNER;
        float a0 = 0.f, a2 = 0.f;
        for (int k4 = 0; k4 < DINNER / 4; k4++) {
            float4 xv = *(const float4*)&xp[p][k4 * 4];
            a0 += dot4(*(const float4*)(w0 + k4 * 4), xv);
            if (og < 8) a2 += dot4(*(const float4*)(w2 + k4 * 4), xv);
        }
        dbl[p][og] = a0;
        if (og < 8) dbl[p][og + 32] = a2;
    }
    __syncthreads();

    // dt_proj + softplus + local chunk scan; thread = channel d
    {
        int d = t;
        float4 dwa = *(const float4*)(dw + d * 8);
        float4 dwb = *(const float4*)(dw + d * 8 + 4);
        float dbv = db[d];
        float dreg[LCH];
        #pragma unroll
        for (int p = 0; p < LCH; p++) {
            float v = dbv
                + dbl[p][0]*dwa.x + dbl[p][1]*dwa.y + dbl[p][2]*dwa.z + dbl[p][3]*dwa.w
                + dbl[p][4]*dwb.x + dbl[p][5]*dwb.y + dbl[p][6]*dwb.z + dbl[p][7]*dwb.w;
            dreg[p] = softplus_f(v);
            delta_out[(size_t)(pos0 + p) * DINNER + d] = dreg[p];
        }
        float Ar[DSTATE];
        const float4* Alp = (const float4*)(A_log + d * DSTATE);
        #pragma unroll
        for (int n4 = 0; n4 < 4; n4++) {
            float4 av = Alp[n4];
            Ar[n4*4+0] = -__expf(av.x);
            Ar[n4*4+1] = -__expf(av.y);
            Ar[n4*4+2] = -__expf(av.z);
            Ar[n4*4+3] = -__expf(av.w);
        }
        float Dd = Dv[d];
        float hs[DSTATE], S[DSTATE];
        #pragma unroll
        for (int n = 0; n < DSTATE; n++) { hs[n] = 0.f; S[n] = 0.f; }
        #pragma unroll
        for (int tt = 0; tt < LCH; tt++) {
            float dlt = dreg[tt];
            float uu  = xp[tt][d];
            float du  = dlt * uu;
            float acc = uu * Dd;
            #pragma unroll
            for (int n = 0; n < DSTATE; n++) {
                float xx = dlt * Ar[n];
                S[n] += xx;
                float a = __expf(xx);
                hs[n] = fmaf(a, hs[n], du * dbl[tt][8 + n]);
                acc = fmaf(hs[n], dbl[tt][24 + n], acc);
            }
            y[(size_t)(pos0 + tt) * DINNER + d] = acc;
        }
        float* Pp = P  + ((size_t)(b * NCH + c) * DINNER + d) * DSTATE;
        float* hp = hF + ((size_t)(b * NCH + c) * DINNER + d) * DSTATE;
        #pragma unroll
        for (int n = 0; n < DSTATE; n++) { Pp[n] = __expf(S[n]); hp[n] = hs[n]; }
    }
    // store C rows for K_C
    if (t < LCH * DSTATE) {
        int p = t >> 4, n = t & 15;
        Cm[(size_t)(pos0 + p) * DSTATE + n] = dbl[p][24 + n];
    }
}

// ---------------- combine: serial over chunks, 16-deep dbuf prefetch ------
__global__ __launch_bounds__(256)
void k_combine(const float* __restrict__ P, const float* __restrict__ hF,
               float* __restrict__ hin)
{
    int idx = blockIdx.x * 256 + threadIdx.x;
    if (idx >= BB * DINNER * DSTATE) return;
    int b = idx >> 12;                 // DINNER*DSTATE = 4096
    int rem = idx & 4095;
    size_t base = (size_t)b * NCH * 4096 + rem;
    const float* Pp = P + base;
    const float* hp = hF + base;
    float* hi = hin + base;
    float pA[CB], hA[CB], pB[CB], hB[CB];
    #pragma unroll
    for (int i = 0; i < CB; i++) {
        pA[i] = Pp[(size_t)i * 4096];
        hA[i] = hp[(size_t)i * 4096];
    }
    float hcur = 0.f;
    for (int bt = 0; bt < NCH / CB; ++bt) {
        if (bt + 1 < NCH / CB) {
            #pragma unroll
            for (int i = 0; i < CB; i++) {
                pB[i] = Pp[((size_t)(bt + 1) * CB + i) * 4096];
                hB[i] = hp[((size_t)(bt + 1) * CB + i) * 4096];
            }
        }
        #pragma unroll
        for (int i = 0; i < CB; i++) {
            hi[((size_t)bt * CB + i) * 4096] = hcur;
            hcur = fmaf(pA[i], hcur, hA[i]);
        }
        #pragma unroll
        for (int i = 0; i < CB; i++) { pA[i] = pB[i]; hA[i] = hB[i]; }
    }
}

// ---------------- K_C: correction + gate + out_proj + residual ------------
__global__ __launch_bounds__(256, 4)
void k_layer_c(const float* __restrict__ delta, const float* __restrict__ Cm,
               const float* __restrict__ A_log, const float* __restrict__ hin,
               const float* __restrict__ y, const float* __restrict__ z,
               const float* __restrict__ Wout, float* __restrict__ h)
{
    __shared__ float Cs[LCH][DSTATE];
    __shared__ float yg[LCH][260];
    int c = blockIdx.x, b = blockIdx.y;
    int t0 = c * LCH;
    int pos0 = b * LSEQ + t0;
    int t = threadIdx.x;
    if (t < LCH * DSTATE) {
        int p = t >> 4, n = t & 15;
        Cs[p][n] = Cm[(size_t)(pos0 + p) * DSTATE + n];
    }
    __syncthreads();
    {   // correction + gate; thread = channel d
        int d = t;
        float Ar[DSTATE], w[DSTATE];
        const float4* Alp = (const float4*)(A_log + d * DSTATE);
        #pragma unroll
        for (int n4 = 0; n4 < 4; n4++) {
            float4 av = Alp[n4];
            Ar[n4*4+0] = -__expf(av.x);
            Ar[n4*4+1] = -__expf(av.y);
            Ar[n4*4+2] = -__expf(av.z);
            Ar[n4*4+3] = -__expf(av.w);
        }
        const float4* hp4 = (const float4*)(hin + ((size_t)(b * NCH + c) * DINNER + d) * DSTATE);
        #pragma unroll
        for (int n4 = 0; n4 < 4; n4++) {
            float4 hv = hp4[n4];
            w[n4*4+0] = hv.x; w[n4*4+1] = hv.y; w[n4*4+2] = hv.z; w[n4*4+3] = hv.w;
        }
        #pragma unroll
        for (int tt = 0; tt < LCH; tt++) {
            float dlt = delta[(size_t)(pos0 + tt) * DINNER + d];
            float corr = 0.f;
            #pragma unroll
            for (int n = 0; n < DSTATE; n++) {
                w[n] *= __expf(dlt * Ar[n]);
                corr = fmaf(w[n], Cs[tt][n], corr);
            }
            float yv = y[(size_t)(pos0 + tt) * DINNER + d] + corr;
            float zv = z[(size_t)(pos0 + tt) * DINNER + d];
            yg[tt][d] = yv * silu_f(zv);
        }
    }
    __syncthreads();
    {   // out_proj: thread = (og = t>>3 owns 4 W rows, p = t&7)
        int p = t & 7, og = t >> 3;
        float acc[4];
        #pragma unroll
        for (int j = 0; j < 4; j++) acc[j] = 0.f;
        const float* wb = Wout + (size_t)og * 4 * DINNER;
        #pragma unroll 2
        for (int k4 = 0; k4 < DINNER / 4; k4++) {
            float4 xv = *(const float4*)&yg[p][k4 * 4];
            #pragma unroll
            for (int j = 0; j < 4; j++)
                acc[j] += dot4(*(const float4*)(wb + j * DINNER + k4 * 4), xv);
        }
        float* hrow = h + (size_t)(pos0 + p) * DMODEL + og * 4;
        float4 h0 = *(float4*)(hrow);
        h0.x += acc[0]; h0.y += acc[1]; h0.z += acc[2]; h0.w += acc[3];
        *(float4*)(hrow) = h0;
    }
}

// ---------------- head: mean-pool + classifier ---------------------------
__global__ __launch_bounds__(256)
void k_head(const float* __restrict__ h, const float* __restrict__ hw,
            const float* __restrict__ hb, float* __restrict__ out)
{
    __shared__ float part[256];
    __shared__ float pool[DMODEL];
    int b = blockIdx.x;
    int t = threadIdx.x;
    int m = t & 127, half = t >> 7;
    float s = 0.f;
    const float* hp = h + (size_t)(b * LSEQ + half * (LSEQ / 2)) * DMODEL + m;
    for (int l = 0; l < LSEQ / 2; l++) s += hp[l * DMODEL];
    part[t] = s;
    __syncthreads();
    if (t < DMODEL) pool[t] = (part[t] + part[t + 128]) * (1.f / LSEQ);
    __syncthreads();
    if (t < 35) {
        const float* wr = hw + t * DMODEL;
        float acc = hb[t];
        for (int k = 0; k < DMODEL; k++) acc += pool[k] * wr[k];
        out[b * 35 + t] = acc;
    }
}

extern "C" void kernel_launch(void* const* d_in, const int* in_sizes, int n_in,
                              void* d_out, int out_size, void* d_ws, size_t ws_size,
                              hipStream_t stream)
{
    const float* x       = (const float*)d_in[0];
    const float* stem_w  = (const float*)d_in[1];
    const float* stem_b  = (const float*)d_in[2];
    const float* ln_g    = (const float*)d_in[3];
    const float* ln_b    = (const float*)d_in[4];
    const float* in_w    = (const float*)d_in[5];
    const float* conv_w  = (const float*)d_in[6];
    const float* conv_b  = (const float*)d_in[7];
    const float* xw      = (const float*)d_in[8];
    const float* dt_w    = (const float*)d_in[9];
    const float* dt_b    = (const float*)d_in[10];
    const float* A_log   = (const float*)d_in[11];
    const float* Dv      = (const float*)d_in[12];
    const float* out_w   = (const float*)d_in[13];
    const float* head_w  = (const float*)d_in[14];
    const float* head_b  = (const float*)d_in[15];
    float* out = (float*)d_out;

    float* ws     = (float*)d_ws;
    float* h      = ws;
    float* zbuf   = h    + (size_t)BB * LSEQ * DMODEL;
    float* dbuf   = zbuf + (size_t)BB * LSEQ * DINNER;
    float* Cmb    = dbuf + (size_t)BB * LSEQ * DINNER;
    float* ybuf   = Cmb  + (size_t)BB * LSEQ * DSTATE;
    float* Pb     = ybuf + (size_t)BB * LSEQ * DINNER;
    float* hFb    = Pb   + (size_t)BB * NCH * DINNER * DSTATE;
    float* hinb   = hFb  + (size_t)BB * NCH * DINNER * DSTATE;

    k_stem<<<(BB * LSEQ * DMODEL + 255) / 256, 256, 0, stream>>>(x, stem_w, stem_b, h);

    dim3 gs(NCH, BB);
    for (int ly = 0; ly < NLAYERS; ly++) {
        k_layer_a<<<gs, 256, 0, stream>>>(
            h, ln_g + ly * DMODEL, ln_b + ly * DMODEL,
            in_w + (size_t)ly * 2 * DINNER * DMODEL,
            conv_w + (size_t)ly * DINNER * 4, conv_b + (size_t)ly * DINNER,
            xw + (size_t)ly * 40 * DINNER, dt_w + (size_t)ly * DINNER * 8,
            dt_b + (size_t)ly * DINNER, A_log + (size_t)ly * DINNER * DSTATE,
            Dv + (size_t)ly * DINNER,
            zbuf, dbuf, Cmb, ybuf, Pb, hFb);
        k_combine<<<(BB * DINNER * DSTATE + 255) / 256, 256, 0, stream>>>(Pb, hFb, hinb);
        k_layer_c<<<gs, 256, 0, stream>>>(
            dbuf, Cmb, A_log + (size_t)ly * DINNER * DSTATE, hinb,
            ybuf, zbuf, out_w + (size_t)ly * DMODEL * DINNER, h);
    }
    k_head<<<BB, 256, 0, stream>>>(h, head_w, head_b, out);
}

// Round 6
// 725.754 us; speedup vs baseline: 1.6056x; 1.6056x over previous
//
#include <hip/hip_runtime.h>
#include <math.h>

#define BB 4
#define LSEQ 2048
#define DMODEL 128
#define DINNER 256
#define DSTATE 16
#define NLAYERS 8
#define NCH 128    // scan chunk count
#define LCH 16     // scan chunk length
#define CB 16      // combine prefetch batch

typedef __attribute__((ext_vector_type(8))) short short8;
typedef __attribute__((ext_vector_type(4))) float f32x4;

__device__ __forceinline__ float silu_f(float x) {
    return x / (1.0f + __expf(-x));
}
__device__ __forceinline__ float softplus_f(float x) {
    return (x > 20.0f) ? x : log1pf(__expf(x));
}
__device__ __forceinline__ float dot4(float4 a, float4 b) {
    return a.x*b.x + a.y*b.y + a.z*b.z + a.w*b.w;
}
__device__ __forceinline__ unsigned short f2bf(float f) {   // RNE
    unsigned int u = __builtin_bit_cast(unsigned int, f);
    u = (u + 0x7fff + ((u >> 16) & 1)) >> 16;
    return (unsigned short)u;
}

// ---------------- weight repack: in_w -> bf16 MFMA B-fragment order -------
// Wib[ly][nt(32)][ks(4)][lane(64)][i(8)]; B[k][out]=in_w[out][k]
__global__ __launch_bounds__(256)
void k_cvt_in(const float* __restrict__ in_w, unsigned short* __restrict__ Wib)
{
    int idx = blockIdx.x * 256 + threadIdx.x;
    if (idx >= NLAYERS * 65536) return;
    int i    = idx & 7;
    int lane = (idx >> 3) & 63;
    int ks   = (idx >> 9) & 3;
    int nt   = (idx >> 11) & 31;
    int ly   = idx >> 16;
    int out  = nt * 16 + (lane & 15);
    int k    = ks * 32 + (lane >> 4) * 8 + i;
    Wib[idx] = f2bf(in_w[((size_t)ly * 512 + out) * DMODEL + k]);
}

// Wob[ly][nt(8)][ks(8)][lane(64)][i(8)]; B[k][out]=out_w[out][k]
__global__ __launch_bounds__(256)
void k_cvt_out(const float* __restrict__ out_w, unsigned short* __restrict__ Wob)
{
    int idx = blockIdx.x * 256 + threadIdx.x;
    if (idx >= NLAYERS * 32768) return;
    int i    = idx & 7;
    int lane = (idx >> 3) & 63;
    int ks   = (idx >> 9) & 7;
    int nt   = (idx >> 12) & 7;
    int ly   = idx >> 15;
    int out  = nt * 16 + (lane & 15);
    int k    = ks * 32 + (lane >> 4) * 8 + i;
    Wob[idx] = f2bf(out_w[((size_t)ly * DMODEL + out) * DINNER + k]);
}

// ---------------- stem ----------------------------------------------------
__global__ __launch_bounds__(256)
void k_stem(const float* __restrict__ x, const float* __restrict__ sw,
            const float* __restrict__ sb, float* __restrict__ h)
{
    int i = blockIdx.x * 256 + threadIdx.x;
    if (i >= BB * LSEQ * DMODEL) return;
    int m = i & (DMODEL - 1);
    int bl = i >> 7;
    const float* xf = x + bl * 4;
    float4 w = *(const float4*)(sw + m * 4);
    h[i] = sb[m] + xf[0]*w.x + xf[1]*w.y + xf[2]*w.z + xf[3]*w.w;
}

// ---------------- K1: LN + in_proj via MFMA -------------------------------
// grid (64, BB): 32 positions/block, 256 threads (4 waves).
// wave w owns output channels w*128..w*128+127 (w<2 -> xp_pre, else z).
__global__ __launch_bounds__(256, 2)
void k_gemm_in(const float* __restrict__ h, const float* __restrict__ g,
               const float* __restrict__ bln, const unsigned short* __restrict__ Wfrag,
               float* __restrict__ xp_pre, float* __restrict__ z)
{
    __shared__ unsigned short xnb[32 * 128];   // bf16, XOR-swizzled granules
    int pos0 = blockIdx.x * 32;
    int b = blockIdx.y;
    int t = threadIdx.x;

    {   // LayerNorm: row = t>>3, 8 lanes/row, 16 ch/lane
        int row = t >> 3, lane = t & 7;
        const float* hp = h + ((size_t)(b * LSEQ + pos0 + row)) * DMODEL + lane * 16;
        float v[16];
        #pragma unroll
        for (int q = 0; q < 4; q++) {
            float4 lv = *(const float4*)(hp + q * 4);
            v[q*4+0] = lv.x; v[q*4+1] = lv.y; v[q*4+2] = lv.z; v[q*4+3] = lv.w;
        }
        float s = 0.f;
        #pragma unroll
        for (int j = 0; j < 16; j++) s += v[j];
        #pragma unroll
        for (int off = 4; off > 0; off >>= 1) s += __shfl_xor(s, off, 8);
        float mu = s * (1.f / DMODEL);
        float vs = 0.f;
        #pragma unroll
        for (int j = 0; j < 16; j++) { float dv = v[j] - mu; vs += dv * dv; }
        #pragma unroll
        for (int off = 4; off > 0; off >>= 1) vs += __shfl_xor(vs, off, 8);
        float rstd = rsqrtf(vs * (1.f / DMODEL) + 1e-5f);
        #pragma unroll
        for (int gi = 0; gi < 2; gi++) {
            unsigned short tmp[8];
            #pragma unroll
            for (int j = 0; j < 8; j++) {
                int ch = lane * 16 + gi * 8 + j;
                tmp[j] = f2bf((v[gi*8+j] - mu) * rstd * g[ch] + bln[ch]);
            }
            int gr = lane * 2 + gi;
            short8 sv;
            #pragma unroll
            for (int j = 0; j < 8; j++) sv[j] = (short)tmp[j];
            *(short8*)&xnb[row * 128 + (gr ^ (row & 15)) * 8] = sv;
        }
    }
    __syncthreads();

    int w = t >> 6, l = t & 63;
    int col = l & 15, kg = l >> 4;
    f32x4 acc[2][8];
    #pragma unroll
    for (int mt = 0; mt < 2; mt++)
        #pragma unroll
        for (int nt = 0; nt < 8; nt++)
            #pragma unroll
            for (int r = 0; r < 4; r++) acc[mt][nt][r] = 0.f;

    #pragma unroll
    for (int ks = 0; ks < 4; ks++) {
        int sw = ((ks * 4 + kg) ^ col) * 8;
        short8 a0 = *(const short8*)&xnb[col * 128 + sw];
        short8 a1 = *(const short8*)&xnb[(col + 16) * 128 + sw];
        #pragma unroll
        for (int nt = 0; nt < 8; nt++) {
            short8 bv = *(const short8*)(Wfrag + (((size_t)(w * 8 + nt) * 4 + ks) * 64 + l) * 8);
            acc[0][nt] = __builtin_amdgcn_mfma_f32_16x16x32_bf16(a0, bv, acc[0][nt], 0, 0, 0);
            acc[1][nt] = __builtin_amdgcn_mfma_f32_16x16x32_bf16(a1, bv, acc[1][nt], 0, 0, 0);
        }
    }
    // epilogue: D row=(l>>4)*4+r, col=l&15
    int rq = l >> 4;
    float* dst = (w < 2) ? xp_pre : z;
    #pragma unroll
    for (int mt = 0; mt < 2; mt++)
        #pragma unroll
        for (int nt = 0; nt < 8; nt++)
            #pragma unroll
            for (int r = 0; r < 4; r++) {
                int pos = pos0 + mt * 16 + rq * 4 + r;
                int ch = (w * 128 + nt * 16 + col) & 255;
                dst[((size_t)(b * LSEQ + pos)) * DINNER + ch] = acc[mt][nt][r];
            }
}

// ---------------- K2: conv+silu+x_proj+dt+softplus+local scan -------------
// grid (NCH, BB), 256 threads.
__global__ __launch_bounds__(256, 4)
void k_scan(const float* __restrict__ xp_pre, const float* __restrict__ cw,
            const float* __restrict__ cb, const float* __restrict__ xw,
            const float* __restrict__ dw, const float* __restrict__ db,
            const float* __restrict__ A_log, const float* __restrict__ Dv,
            float* __restrict__ delta_out, float* __restrict__ Cm,
            float* __restrict__ y, float* __restrict__ P, float* __restrict__ hF)
{
    __shared__ float xs[LCH + 3][260];
    __shared__ float dbl[LCH][40];
    int c = blockIdx.x, b = blockIdx.y;
    int t0 = c * LCH;
    int pos0 = b * LSEQ + t0;
    int t = threadIdx.x;
    for (int j = t; j < (LCH + 3) * DINNER; j += 256) {
        int r = j >> 8, d = j & 255;
        int l = t0 - 3 + r;
        xs[r][d] = (l < 0) ? 0.f : xp_pre[(size_t)(b * LSEQ + l) * DINNER + d];
    }
    __syncthreads();
    {   // conv + silu in place
        int d = t;
        float4 cwv = *(const float4*)(cw + d * 4);
        float cbv = cb[d];
        float q0 = xs[0][d], q1 = xs[1][d], q2 = xs[2][d];
        #pragma unroll
        for (int p = 0; p < LCH; p++) {
            float cur = xs[p + 3][d];
            float xc = cbv + q0*cwv.x + q1*cwv.y + q2*cwv.z + cur*cwv.w;
            xs[p][d] = silu_f(xc);
            q0 = q1; q1 = q2; q2 = cur;
        }
    }
    __syncthreads();
    {   // x_proj (broadcast W from L2): og -> outs og, og+16, (og<8) og+32
        int p = t & 15, og = t >> 4;
        const float* w0 = xw + (size_t)og * DINNER;
        const float* w1 = xw + (size_t)(og + 16) * DINNER;
        const float* w2 = xw + (size_t)(og + 32) * DINNER;
        float a0 = 0.f, a1 = 0.f, a2 = 0.f;
        for (int k4 = 0; k4 < DINNER / 4; k4++) {
            float4 xv = *(const float4*)&xs[p][k4 * 4];
            a0 += dot4(*(const float4*)(w0 + k4 * 4), xv);
            a1 += dot4(*(const float4*)(w1 + k4 * 4), xv);
            if (og < 8) a2 += dot4(*(const float4*)(w2 + k4 * 4), xv);
        }
        dbl[p][og]      = a0;
        dbl[p][og + 16] = a1;
        if (og < 8) dbl[p][og + 32] = a2;
    }
    __syncthreads();
    {   // dt_proj + softplus + local scan; thread = channel d
        int d = t;
        float4 dwa = *(const float4*)(dw + d * 8);
        float4 dwb = *(const float4*)(dw + d * 8 + 4);
        float dbv = db[d];
        float dreg[LCH];
        #pragma unroll
        for (int p = 0; p < LCH; p++) {
            float v = dbv
                + dbl[p][0]*dwa.x + dbl[p][1]*dwa.y + dbl[p][2]*dwa.z + dbl[p][3]*dwa.w
                + dbl[p][4]*dwb.x + dbl[p][5]*dwb.y + dbl[p][6]*dwb.z + dbl[p][7]*dwb.w;
            dreg[p] = softplus_f(v);
            delta_out[(size_t)(pos0 + p) * DINNER + d] = dreg[p];
        }
        float Ar[DSTATE];
        const float4* Alp = (const float4*)(A_log + d * DSTATE);
        #pragma unroll
        for (int n4 = 0; n4 < 4; n4++) {
            float4 av = Alp[n4];
            Ar[n4*4+0] = -__expf(av.x);
            Ar[n4*4+1] = -__expf(av.y);
            Ar[n4*4+2] = -__expf(av.z);
            Ar[n4*4+3] = -__expf(av.w);
        }
        float Dd = Dv[d];
        float hs[DSTATE], S[DSTATE];
        #pragma unroll
        for (int n = 0; n < DSTATE; n++) { hs[n] = 0.f; S[n] = 0.f; }
        for (int tt = 0; tt < LCH; tt++) {
            float dlt = dreg[tt];
            float uu  = xs[tt][d];
            float du  = dlt * uu;
            float acc = uu * Dd;
            #pragma unroll
            for (int n = 0; n < DSTATE; n++) {
                float xx = dlt * Ar[n];
                S[n] += xx;
                float a = __expf(xx);
                hs[n] = fmaf(a, hs[n], du * dbl[tt][8 + n]);
                acc = fmaf(hs[n], dbl[tt][24 + n], acc);
            }
            y[(size_t)(pos0 + tt) * DINNER + d] = acc;
        }
        float* Pp = P  + ((size_t)(b * NCH + c) * DINNER + d) * DSTATE;
        float* hp = hF + ((size_t)(b * NCH + c) * DINNER + d) * DSTATE;
        #pragma unroll
        for (int n = 0; n < DSTATE; n++) { Pp[n] = __expf(S[n]); hp[n] = hs[n]; }
    }
    {   // store C rows
        int p = t >> 4, n = t & 15;
        Cm[(size_t)(pos0 + p) * DSTATE + n] = dbl[p][24 + n];
    }
}

// ---------------- combine (hin may alias P) -------------------------------
__global__ __launch_bounds__(256)
void k_combine(const float* __restrict__ P, const float* __restrict__ hF,
               float* __restrict__ hin)
{
    int idx = blockIdx.x * 256 + threadIdx.x;
    if (idx >= BB * DINNER * DSTATE) return;
    int b = idx >> 12;
    int rem = idx & 4095;
    size_t base = (size_t)b * NCH * 4096 + rem;
    const float* Pp = P + base;
    const float* hp = hF + base;
    float* hi = hin + base;
    float pA[CB], hA[CB], pB[CB], hB[CB];
    #pragma unroll
    for (int i = 0; i < CB; i++) {
        pA[i] = Pp[(size_t)i * 4096];
        hA[i] = hp[(size_t)i * 4096];
    }
    float hcur = 0.f;
    for (int bt = 0; bt < NCH / CB; ++bt) {
        if (bt + 1 < NCH / CB) {
            #pragma unroll
            for (int i = 0; i < CB; i++) {
                pB[i] = Pp[((size_t)(bt + 1) * CB + i) * 4096];
                hB[i] = hp[((size_t)(bt + 1) * CB + i) * 4096];
            }
        }
        #pragma unroll
        for (int i = 0; i < CB; i++) {
            hi[((size_t)bt * CB + i) * 4096] = hcur;
            hcur = fmaf(pA[i], hcur, hA[i]);
        }
        #pragma unroll
        for (int i = 0; i < CB; i++) { pA[i] = pB[i]; hA[i] = hB[i]; }
    }
}

// ---------------- K3: correction + gate + MFMA out_proj + residual --------
// grid (64, BB): 32 positions (2 scan chunks)/block, 256 threads.
__global__ __launch_bounds__(256, 4)
void k_layer_c(const float* __restrict__ delta, const float* __restrict__ Cm,
               const float* __restrict__ A_log, const float* __restrict__ hin,
               const float* __restrict__ y, const float* __restrict__ z,
               const unsigned short* __restrict__ Wfrag, float* __restrict__ h)
{
    __shared__ float Cs[2][LCH][DSTATE];
    __shared__ unsigned short yg[32 * 256];    // bf16, swizzled (32 granules/row)
    int pt = blockIdx.x, b = blockIdx.y;
    int pos0 = pt * 32;
    int t = threadIdx.x;
    for (int j = t; j < 2 * LCH * DSTATE; j += 256) {
        int cc = j >> 8, p = (j >> 4) & 15, n = j & 15;
        Cs[cc][p][n] = Cm[(size_t)(b * LSEQ + pos0 + cc * 16 + p) * DSTATE + n];
    }
    __syncthreads();
    {   // correction + gate; thread = channel d, two chunks
        int d = t;
        float Ar[DSTATE];
        const float4* Alp = (const float4*)(A_log + d * DSTATE);
        #pragma unroll
        for (int n4 = 0; n4 < 4; n4++) {
            float4 av = Alp[n4];
            Ar[n4*4+0] = -__expf(av.x);
            Ar[n4*4+1] = -__expf(av.y);
            Ar[n4*4+2] = -__expf(av.z);
            Ar[n4*4+3] = -__expf(av.w);
        }
        #pragma unroll
        for (int cc = 0; cc < 2; cc++) {
            int cg = pt * 2 + cc;
            float w[DSTATE];
            const float4* hp4 = (const float4*)(hin + ((size_t)(b * NCH + cg) * DINNER + d) * DSTATE);
            #pragma unroll
            for (int n4 = 0; n4 < 4; n4++) {
                float4 hv = hp4[n4];
                w[n4*4+0] = hv.x; w[n4*4+1] = hv.y; w[n4*4+2] = hv.z; w[n4*4+3] = hv.w;
            }
            for (int tt = 0; tt < LCH; tt++) {
                size_t gpos = (size_t)(b * LSEQ + pos0 + cc * 16 + tt) * DINNER + d;
                float dlt = delta[gpos];
                float corr = 0.f;
                #pragma unroll
                for (int n = 0; n < DSTATE; n++) {
                    w[n] *= __expf(dlt * Ar[n]);
                    corr = fmaf(w[n], Cs[cc][tt][n], corr);
                }
                float yv = y[gpos] + corr;
                float zv = z[gpos];
                int row = cc * 16 + tt;
                yg[row * 256 + (((d >> 3) ^ (row & 31)) * 8) + (d & 7)] =
                    f2bf(yv * silu_f(zv));
            }
        }
    }
    __syncthreads();
    {   // out_proj MFMA: wave w -> Mtile w>>1, out-half w&1
        int w = t >> 6, l = t & 63;
        int col = l & 15, kg = l >> 4;
        int mt = w >> 1, nh = w & 1;
        int row = mt * 16 + col;
        f32x4 acc[4];
        #pragma unroll
        for (int nt = 0; nt < 4; nt++)
            #pragma unroll
            for (int r = 0; r < 4; r++) acc[nt][r] = 0.f;
        #pragma unroll
        for (int ks = 0; ks < 8; ks++) {
            short8 a0 = *(const short8*)&yg[row * 256 + (((ks * 4 + kg) ^ (row & 31)) * 8)];
            #pragma unroll
            for (int nt = 0; nt < 4; nt++) {
                short8 bv = *(const short8*)(Wfrag + (((size_t)(nh * 4 + nt) * 8 + ks) * 64 + l) * 8);
                acc[nt] = __builtin_amdgcn_mfma_f32_16x16x32_bf16(a0, bv, acc[nt], 0, 0, 0);
            }
        }
        int rq = l >> 4;
        #pragma unroll
        for (int nt = 0; nt < 4; nt++)
            #pragma unroll
            for (int r = 0; r < 4; r++) {
                int pos = pos0 + mt * 16 + rq * 4 + r;
                int ch = nh * 64 + nt * 16 + col;
                h[((size_t)(b * LSEQ + pos)) * DMODEL + ch] += acc[nt][r];
            }
    }
}

// ---------------- head: mean-pool + classifier ---------------------------
__global__ __launch_bounds__(256)
void k_head(const float* __restrict__ h, const float* __restrict__ hw,
            const float* __restrict__ hb, float* __restrict__ out)
{
    __shared__ float part[256];
    __shared__ float pool[DMODEL];
    int b = blockIdx.x;
    int t = threadIdx.x;
    int m = t & 127, half = t >> 7;
    float s = 0.f;
    const float* hp = h + (size_t)(b * LSEQ + half * (LSEQ / 2)) * DMODEL + m;
    for (int l = 0; l < LSEQ / 2; l++) s += hp[l * DMODEL];
    part[t] = s;
    __syncthreads();
    if (t < DMODEL) pool[t] = (part[t] + part[t + 128]) * (1.f / LSEQ);
    __syncthreads();
    if (t < 35) {
        const float* wr = hw + t * DMODEL;
        float acc = hb[t];
        for (int k = 0; k < DMODEL; k++) acc += pool[k] * wr[k];
        out[b * 35 + t] = acc;
    }
}

extern "C" void kernel_launch(void* const* d_in, const int* in_sizes, int n_in,
                              void* d_out, int out_size, void* d_ws, size_t ws_size,
                              hipStream_t stream)
{
    const float* x       = (const float*)d_in[0];
    const float* stem_w  = (const float*)d_in[1];
    const float* stem_b  = (const float*)d_in[2];
    const float* ln_g    = (const float*)d_in[3];
    const float* ln_b    = (const float*)d_in[4];
    const float* in_w    = (const float*)d_in[5];
    const float* conv_w  = (const float*)d_in[6];
    const float* conv_b  = (const float*)d_in[7];
    const float* xw      = (const float*)d_in[8];
    const float* dt_w    = (const float*)d_in[9];
    const float* dt_b    = (const float*)d_in[10];
    const float* A_log   = (const float*)d_in[11];
    const float* Dv      = (const float*)d_in[12];
    const float* out_w   = (const float*)d_in[13];
    const float* head_w  = (const float*)d_in[14];
    const float* head_b  = (const float*)d_in[15];
    float* out = (float*)d_out;

    float* ws     = (float*)d_ws;
    float* h      = ws;
    float* xpbuf  = h     + (size_t)BB * LSEQ * DMODEL;
    float* zbuf   = xpbuf + (size_t)BB * LSEQ * DINNER;
    float* dbuf   = zbuf  + (size_t)BB * LSEQ * DINNER;
    float* Cmb    = dbuf  + (size_t)BB * LSEQ * DINNER;
    float* ybuf   = Cmb   + (size_t)BB * LSEQ * DSTATE;
    float* Pb     = ybuf  + (size_t)BB * LSEQ * DINNER;
    float* hFb    = Pb    + (size_t)BB * NCH * DINNER * DSTATE;
    float* wend   = hFb   + (size_t)BB * NCH * DINNER * DSTATE;
    unsigned short* Wib = (unsigned short*)wend;
    unsigned short* Wob = Wib + (size_t)NLAYERS * 65536;
    float* hinb = Pb;   // alias: combine overwrites P with hin (safe, see kernel)

    k_cvt_in<<<(NLAYERS * 65536 + 255) / 256, 256, 0, stream>>>(in_w, Wib);
    k_cvt_out<<<(NLAYERS * 32768 + 255) / 256, 256, 0, stream>>>(out_w, Wob);
    k_stem<<<(BB * LSEQ * DMODEL + 255) / 256, 256, 0, stream>>>(x, stem_w, stem_b, h);

    dim3 g_gemm(LSEQ / 32, BB);
    dim3 g_scan(NCH, BB);
    for (int ly = 0; ly < NLAYERS; ly++) {
        k_gemm_in<<<g_gemm, 256, 0, stream>>>(
            h, ln_g + ly * DMODEL, ln_b + ly * DMODEL,
            Wib + (size_t)ly * 65536, xpbuf, zbuf);
        k_scan<<<g_scan, 256, 0, stream>>>(
            xpbuf, conv_w + (size_t)ly * DINNER * 4, conv_b + (size_t)ly * DINNER,
            xw + (size_t)ly * 40 * DINNER, dt_w + (size_t)ly * DINNER * 8,
            dt_b + (size_t)ly * DINNER, A_log + (size_t)ly * DINNER * DSTATE,
            Dv + (size_t)ly * DINNER,
            dbuf, Cmb, ybuf, Pb, hFb);
        k_combine<<<(BB * DINNER * DSTATE + 255) / 256, 256, 0, stream>>>(Pb, hFb, hinb);
        k_layer_c<<<g_gemm, 256, 0, stream>>>(
            dbuf, Cmb, A_log + (size_t)ly * DINNER * DSTATE, hinb,
            ybuf, zbuf, Wob + (size_t)ly * 32768, h);
    }
    k_head<<<BB, 256, 0, stream>>>(h, head_w, head_b, out);
}

// Round 7
// 575.522 us; speedup vs baseline: 2.0248x; 1.2610x over previous
//
#include <hip/hip_runtime.h>
#include <math.h>

#define BB 4
#define LSEQ 2048
#define DMODEL 128
#define DINNER 256
#define DSTATE 16
#define NLAYERS 8
#define NCH 256    // scan chunk count
#define LCH 8      // scan chunk length
#define HALO 3
#define VROWS 11   // LCH + HALO valid rows
#define CB 16      // combine prefetch batch

typedef __attribute__((ext_vector_type(8))) short short8;
typedef __attribute__((ext_vector_type(4))) float f32x4;

__device__ __forceinline__ float silu_f(float x) {
    return x / (1.0f + __expf(-x));
}
__device__ __forceinline__ float softplus_f(float x) {
    return (x > 20.0f) ? x : log1pf(__expf(x));
}
__device__ __forceinline__ unsigned short f2bf(float f) {   // RNE
    unsigned int u = __builtin_bit_cast(unsigned int, f);
    u = (u + 0x7fff + ((u >> 16) & 1)) >> 16;
    return (unsigned short)u;
}

// ---------------- weight repacks to bf16 MFMA B-fragment order ------------
// Wib[ly][nt(32)][ks(4)][lane(64)][i(8)]; B[k][out]=in_w[out][k]
__global__ __launch_bounds__(256)
void k_cvt_in(const float* __restrict__ in_w, unsigned short* __restrict__ Wib)
{
    int idx = blockIdx.x * 256 + threadIdx.x;
    if (idx >= NLAYERS * 65536) return;
    int i    = idx & 7;
    int lane = (idx >> 3) & 63;
    int ks   = (idx >> 9) & 3;
    int nt   = (idx >> 11) & 31;
    int ly   = idx >> 16;
    int out  = nt * 16 + (lane & 15);
    int k    = ks * 32 + (lane >> 4) * 8 + i;
    Wib[idx] = f2bf(in_w[((size_t)ly * 512 + out) * DMODEL + k]);
}

// Wob[ly][nt(8)][ks(8)][lane(64)][i(8)]; B[k][out]=out_w[out][k]
__global__ __launch_bounds__(256)
void k_cvt_out(const float* __restrict__ out_w, unsigned short* __restrict__ Wob)
{
    int idx = blockIdx.x * 256 + threadIdx.x;
    if (idx >= NLAYERS * 32768) return;
    int i    = idx & 7;
    int lane = (idx >> 3) & 63;
    int ks   = (idx >> 9) & 7;
    int nt   = (idx >> 12) & 7;
    int ly   = idx >> 15;
    int out  = nt * 16 + (lane & 15);
    int k    = ks * 32 + (lane >> 4) * 8 + i;
    Wob[idx] = f2bf(out_w[((size_t)ly * DMODEL + out) * DINNER + k]);
}

// Wxb[ly][nt(3)][ks(8)][lane(64)][i(8)]; B[k][o]=xw[o][k], o>=40 -> 0
__global__ __launch_bounds__(256)
void k_cvt_xw(const float* __restrict__ xw, unsigned short* __restrict__ Wxb)
{
    int idx = blockIdx.x * 256 + threadIdx.x;
    if (idx >= NLAYERS * 12288) return;
    int ly  = idx / 12288;
    int rem = idx % 12288;
    int nt   = rem >> 12;
    int ks   = (rem >> 9) & 7;
    int lane = (rem >> 3) & 63;
    int i    = rem & 7;
    int o = nt * 16 + (lane & 15);
    int k = ks * 32 + (lane >> 4) * 8 + i;
    Wxb[idx] = (o < 40) ? f2bf(xw[((size_t)ly * 40 + o) * DINNER + k]) : 0;
}

// ---------------- stem ----------------------------------------------------
__global__ __launch_bounds__(256)
void k_stem(const float* __restrict__ x, const float* __restrict__ sw,
            const float* __restrict__ sb, float* __restrict__ h)
{
    int i = blockIdx.x * 256 + threadIdx.x;
    if (i >= BB * LSEQ * DMODEL) return;
    int m = i & (DMODEL - 1);
    int bl = i >> 7;
    const float* xf = x + bl * 4;
    float4 w = *(const float4*)(sw + m * 4);
    h[i] = sb[m] + xf[0]*w.x + xf[1]*w.y + xf[2]*w.z + xf[3]*w.w;
}

// ---------------- K_A: LN+in_proj(MFMA)+conv+silu+x_proj(MFMA)+dt+scan ----
// grid (NCH, BB), 256 threads (4 waves), 4 blocks/CU.
__global__ __launch_bounds__(256, 4)
void k_fused_a(const float* __restrict__ h, const float* __restrict__ g,
               const float* __restrict__ bln,
               const unsigned short* __restrict__ Wib,
               const unsigned short* __restrict__ Wxb,
               const float* __restrict__ cw, const float* __restrict__ cb,
               const float* __restrict__ dw, const float* __restrict__ db,
               const float* __restrict__ A_log, const float* __restrict__ Dv,
               float* __restrict__ z, float* __restrict__ delta_out,
               float* __restrict__ Cm, float* __restrict__ y,
               float* __restrict__ P, float* __restrict__ hF)
{
    __shared__ unsigned short xnb[16 * 128];  // LN out bf16, swizzled granules
    __shared__ float xp[16][260];             // in_proj xp (fp32), rows 0..10 valid
    __shared__ unsigned short xsb[16 * 256];  // conv+silu out bf16, swizzled
    __shared__ float dbl[LCH][48];            // x_proj out: 0..7 dt, 8..23 B, 24..39 C
    int c = blockIdx.x, b = blockIdx.y;
    int t0 = c * LCH;
    int pos0 = b * LSEQ + t0;                 // global position of chunk start
    int t = threadIdx.x;

    // ---- stage + LayerNorm -> bf16 swizzled LDS (16 lanes/row, 8 ch/lane)
    {
        int r = t >> 4, lane = t & 15;
        int l = t0 - HALO + r;
        bool valid = (l >= 0) && (r < VROWS);
        float v[8];
        if (valid) {
            const float* hp = h + ((size_t)(b * LSEQ + l)) * DMODEL + lane * 8;
            float4 lv0 = *(const float4*)(hp);
            float4 lv1 = *(const float4*)(hp + 4);
            v[0]=lv0.x; v[1]=lv0.y; v[2]=lv0.z; v[3]=lv0.w;
            v[4]=lv1.x; v[5]=lv1.y; v[6]=lv1.z; v[7]=lv1.w;
        } else {
            #pragma unroll
            for (int j = 0; j < 8; j++) v[j] = 0.f;
        }
        float s = 0.f;
        #pragma unroll
        for (int j = 0; j < 8; j++) s += v[j];
        #pragma unroll
        for (int off = 8; off > 0; off >>= 1) s += __shfl_xor(s, off, 16);
        float mu = s * (1.f / DMODEL);
        float vs = 0.f;
        #pragma unroll
        for (int j = 0; j < 8; j++) { float dv = v[j] - mu; vs += dv * dv; }
        #pragma unroll
        for (int off = 8; off > 0; off >>= 1) vs += __shfl_xor(vs, off, 16);
        float rstd = rsqrtf(vs * (1.f / DMODEL) + 1e-5f);
        short8 sv;
        #pragma unroll
        for (int j = 0; j < 8; j++) {
            int ch = lane * 8 + j;
            float o = valid ? ((v[j] - mu) * rstd * g[ch] + bln[ch]) : 0.f;
            sv[j] = (short)f2bf(o);
        }
        *(short8*)&xnb[r * 128 + ((lane ^ r) << 3)] = sv;
    }
    __syncthreads();

    // ---- in_proj MFMA: wave w owns out-ch w*128..+127 (w<2 -> xp, else z)
    {
        int w = t >> 6, l = t & 63;
        int col = l & 15, kg = l >> 4;
        f32x4 acc[8];
        #pragma unroll
        for (int nt = 0; nt < 8; nt++)
            #pragma unroll
            for (int r = 0; r < 4; r++) acc[nt][r] = 0.f;
        #pragma unroll
        for (int ks = 0; ks < 4; ks++) {
            short8 a = *(const short8*)&xnb[col * 128 + (((ks * 4 + kg) ^ col) << 3)];
            #pragma unroll
            for (int nt = 0; nt < 8; nt++) {
                short8 bv = *(const short8*)(Wib + (((size_t)(w * 8 + nt) * 4 + ks) * 64 + l) * 8);
                acc[nt] = __builtin_amdgcn_mfma_f32_16x16x32_bf16(a, bv, acc[nt], 0, 0, 0);
            }
        }
        int rq = l >> 4;
        if (w < 2) {
            #pragma unroll
            for (int nt = 0; nt < 8; nt++)
                #pragma unroll
                for (int r = 0; r < 4; r++)
                    xp[rq * 4 + r][w * 128 + nt * 16 + col] = acc[nt][r];
        } else {
            #pragma unroll
            for (int nt = 0; nt < 8; nt++)
                #pragma unroll
                for (int r = 0; r < 4; r++) {
                    int row = rq * 4 + r;
                    if (row >= HALO && row < VROWS)
                        z[(size_t)(pos0 + row - HALO) * DINNER +
                          (w - 2) * 128 + nt * 16 + col] = acc[nt][r];
                }
        }
    }
    __syncthreads();

    // ---- conv + silu: thread = channel d; u kept in registers
    float ureg[LCH];
    {
        int d = t;
        float4 cwv = *(const float4*)(cw + d * 4);
        float cbv = cb[d];
        float q0 = xp[0][d], q1 = xp[1][d], q2 = xp[2][d];
        int gd = d >> 3, bo = d & 7;
        #pragma unroll
        for (int p = 0; p < LCH; p++) {
            float cur = xp[p + HALO][d];
            float xc = cbv + q0*cwv.x + q1*cwv.y + q2*cwv.z + cur*cwv.w;
            float u = silu_f(xc);
            ureg[p] = u;
            xsb[p * 256 + ((gd ^ (p & 7)) << 3) + bo] = f2bf(u);
            q0 = q1; q1 = q2; q2 = cur;
        }
        #pragma unroll
        for (int p = LCH; p < 16; p++)
            xsb[p * 256 + ((gd ^ (p & 7)) << 3) + bo] = 0;
    }
    __syncthreads();

    // ---- x_proj MFMA: waves 0..2, wave w -> N-tile w (outs w*16..w*16+15)
    {
        int w = t >> 6, l = t & 63;
        if (w < 3) {
            int col = l & 15, kg = l >> 4;
            f32x4 acc;
            #pragma unroll
            for (int r = 0; r < 4; r++) acc[r] = 0.f;
            #pragma unroll
            for (int ks = 0; ks < 8; ks++) {
                int gk = ks * 4 + kg;
                short8 a = *(const short8*)&xsb[col * 256 + ((gk ^ (col & 7)) << 3)];
                short8 bv = *(const short8*)(Wxb + (((size_t)w * 8 + ks) * 64 + l) * 8);
                acc = __builtin_amdgcn_mfma_f32_16x16x32_bf16(a, bv, acc, 0, 0, 0);
            }
            int rq = l >> 4;
            if (rq < 2) {
                #pragma unroll
                for (int r = 0; r < 4; r++)
                    dbl[rq * 4 + r][w * 16 + col] = acc[r];
            }
        }
    }
    __syncthreads();

    // ---- dt_proj + softplus + local scan; thread = channel d
    {
        int d = t;
        float4 dwa = *(const float4*)(dw + d * 8);
        float4 dwb = *(const float4*)(dw + d * 8 + 4);
        float dbv = db[d];
        float dreg[LCH];
        #pragma unroll
        for (int p = 0; p < LCH; p++) {
            float v = dbv
                + dbl[p][0]*dwa.x + dbl[p][1]*dwa.y + dbl[p][2]*dwa.z + dbl[p][3]*dwa.w
                + dbl[p][4]*dwb.x + dbl[p][5]*dwb.y + dbl[p][6]*dwb.z + dbl[p][7]*dwb.w;
            dreg[p] = softplus_f(v);
            delta_out[(size_t)(pos0 + p) * DINNER + d] = dreg[p];
        }
        float Ar[DSTATE];
        const float4* Alp = (const float4*)(A_log + d * DSTATE);
        #pragma unroll
        for (int n4 = 0; n4 < 4; n4++) {
            float4 av = Alp[n4];
            Ar[n4*4+0] = -__expf(av.x);
            Ar[n4*4+1] = -__expf(av.y);
            Ar[n4*4+2] = -__expf(av.z);
            Ar[n4*4+3] = -__expf(av.w);
        }
        float Dd = Dv[d];
        float hs[DSTATE], S[DSTATE];
        #pragma unroll
        for (int n = 0; n < DSTATE; n++) { hs[n] = 0.f; S[n] = 0.f; }
        #pragma unroll
        for (int tt = 0; tt < LCH; tt++) {
            float dlt = dreg[tt];
            float uu  = ureg[tt];
            float du  = dlt * uu;
            float acc = uu * Dd;
            #pragma unroll
            for (int n = 0; n < DSTATE; n++) {
                float xx = dlt * Ar[n];
                S[n] += xx;
                float a = __expf(xx);
                hs[n] = fmaf(a, hs[n], du * dbl[tt][8 + n]);
                acc = fmaf(hs[n], dbl[tt][24 + n], acc);
            }
            y[(size_t)(pos0 + tt) * DINNER + d] = acc;
        }
        float* Pp = P  + ((size_t)(b * NCH + c) * DINNER + d) * DSTATE;
        float* hp = hF + ((size_t)(b * NCH + c) * DINNER + d) * DSTATE;
        #pragma unroll
        for (int n = 0; n < DSTATE; n++) { Pp[n] = __expf(S[n]); hp[n] = hs[n]; }
    }
    // ---- store C rows for K_C
    if (t < LCH * DSTATE) {
        int p = t >> 4, n = t & 15;
        Cm[(size_t)(pos0 + p) * DSTATE + n] = dbl[p][24 + n];
    }
}

// ---------------- combine (hin aliases P; safe) ---------------------------
__global__ __launch_bounds__(256)
void k_combine(const float* __restrict__ P, const float* __restrict__ hF,
               float* __restrict__ hin)
{
    int idx = blockIdx.x * 256 + threadIdx.x;
    if (idx >= BB * DINNER * DSTATE) return;
    int b = idx >> 12;
    int rem = idx & 4095;
    size_t base = (size_t)b * NCH * 4096 + rem;
    const float* Pp = P + base;
    const float* hp = hF + base;
    float* hi = hin + base;
    float pA[CB], hA[CB], pB[CB], hB[CB];
    #pragma unroll
    for (int i = 0; i < CB; i++) {
        pA[i] = Pp[(size_t)i * 4096];
        hA[i] = hp[(size_t)i * 4096];
    }
    float hcur = 0.f;
    for (int bt = 0; bt < NCH / CB; ++bt) {
        if (bt + 1 < NCH / CB) {
            #pragma unroll
            for (int i = 0; i < CB; i++) {
                pB[i] = Pp[((size_t)(bt + 1) * CB + i) * 4096];
                hB[i] = hp[((size_t)(bt + 1) * CB + i) * 4096];
            }
        }
        #pragma unroll
        for (int i = 0; i < CB; i++) {
            hi[((size_t)bt * CB + i) * 4096] = hcur;
            hcur = fmaf(pA[i], hcur, hA[i]);
        }
        #pragma unroll
        for (int i = 0; i < CB; i++) { pA[i] = pB[i]; hA[i] = hB[i]; }
    }
}

// ---------------- K_C: correction + gate + MFMA out_proj + residual -------
// grid (LSEQ/16, BB): 16 positions (2 chunks of 8)/block, 256 threads.
__global__ __launch_bounds__(256, 4)
void k_layer_c(const float* __restrict__ delta, const float* __restrict__ Cm,
               const float* __restrict__ A_log, const float* __restrict__ hin,
               const float* __restrict__ y, const float* __restrict__ z,
               const unsigned short* __restrict__ Wfrag, float* __restrict__ h)
{
    __shared__ float Cs[2][LCH][DSTATE];
    __shared__ unsigned short yg[16 * 256];    // bf16, swizzled
    int pt = blockIdx.x, b = blockIdx.y;
    int pos0 = pt * 16;
    int t = threadIdx.x;
    {
        int j = t;          // 256 = 2*8*16 exactly
        int cc = j >> 7, p = (j >> 4) & 7, n = j & 15;
        Cs[cc][p][n] = Cm[(size_t)(b * LSEQ + pos0 + cc * 8 + p) * DSTATE + n];
    }
    __syncthreads();
    {   // correction + gate; thread = channel d, two chunks of 8
        int d = t;
        float Ar[DSTATE];
        const float4* Alp = (const float4*)(A_log + d * DSTATE);
        #pragma unroll
        for (int n4 = 0; n4 < 4; n4++) {
            float4 av = Alp[n4];
            Ar[n4*4+0] = -__expf(av.x);
            Ar[n4*4+1] = -__expf(av.y);
            Ar[n4*4+2] = -__expf(av.z);
            Ar[n4*4+3] = -__expf(av.w);
        }
        int gd = d >> 3, bo = d & 7;
        #pragma unroll
        for (int cc = 0; cc < 2; cc++) {
            int cg = pt * 2 + cc;
            float w[DSTATE];
            const float4* hp4 = (const float4*)(hin + ((size_t)(b * NCH + cg) * DINNER + d) * DSTATE);
            #pragma unroll
            for (int n4 = 0; n4 < 4; n4++) {
                float4 hv = hp4[n4];
                w[n4*4+0] = hv.x; w[n4*4+1] = hv.y; w[n4*4+2] = hv.z; w[n4*4+3] = hv.w;
            }
            #pragma unroll
            for (int tt = 0; tt < LCH; tt++) {
                size_t gpos = (size_t)(b * LSEQ + pos0 + cc * 8 + tt) * DINNER + d;
                float dlt = delta[gpos];
                float corr = 0.f;
                #pragma unroll
                for (int n = 0; n < DSTATE; n++) {
                    w[n] *= __expf(dlt * Ar[n]);
                    corr = fmaf(w[n], Cs[cc][tt][n], corr);
                }
                float yv = y[gpos] + corr;
                float zv = z[gpos];
                int row = cc * 8 + tt;
                yg[row * 256 + ((gd ^ row) << 3) + bo] = f2bf(yv * silu_f(zv));
            }
        }
    }
    __syncthreads();
    {   // out_proj MFMA: wave w owns N-tiles {2w, 2w+1}; M = 16 positions
        int w = t >> 6, l = t & 63;
        int col = l & 15, kg = l >> 4;
        f32x4 acc[2];
        #pragma unroll
        for (int q = 0; q < 2; q++)
            #pragma unroll
            for (int r = 0; r < 4; r++) acc[q][r] = 0.f;
        #pragma unroll
        for (int ks = 0; ks < 8; ks++) {
            int gk = ks * 4 + kg;
            short8 a0 = *(const short8*)&yg[col * 256 + ((gk ^ col) << 3)];
            #pragma unroll
            for (int q = 0; q < 2; q++) {
                short8 bv = *(const short8*)(Wfrag + (((size_t)(w * 2 + q) * 8 + ks) * 64 + l) * 8);
                acc[q] = __builtin_amdgcn_mfma_f32_16x16x32_bf16(a0, bv, acc[q], 0, 0, 0);
            }
        }
        int rq = l >> 4;
        #pragma unroll
        for (int q = 0; q < 2; q++)
            #pragma unroll
            for (int r = 0; r < 4; r++) {
                int pos = pos0 + rq * 4 + r;
                int ch = (w * 2 + q) * 16 + col;
                h[((size_t)(b * LSEQ + pos)) * DMODEL + ch] += acc[q][r];
            }
    }
}

// ---------------- head: mean-pool + classifier ---------------------------
__global__ __launch_bounds__(256)
void k_head(const float* __restrict__ h, const float* __restrict__ hw,
            const float* __restrict__ hb, float* __restrict__ out)
{
    __shared__ float part[256];
    __shared__ float pool[DMODEL];
    int b = blockIdx.x;
    int t = threadIdx.x;
    int m = t & 127, half = t >> 7;
    float s = 0.f;
    const float* hp = h + (size_t)(b * LSEQ + half * (LSEQ / 2)) * DMODEL + m;
    for (int l = 0; l < LSEQ / 2; l++) s += hp[l * DMODEL];
    part[t] = s;
    __syncthreads();
    if (t < DMODEL) pool[t] = (part[t] + part[t + 128]) * (1.f / LSEQ);
    __syncthreads();
    if (t < 35) {
        const float* wr = hw + t * DMODEL;
        float acc = hb[t];
        for (int k = 0; k < DMODEL; k++) acc += pool[k] * wr[k];
        out[b * 35 + t] = acc;
    }
}

extern "C" void kernel_launch(void* const* d_in, const int* in_sizes, int n_in,
                              void* d_out, int out_size, void* d_ws, size_t ws_size,
                              hipStream_t stream)
{
    const float* x       = (const float*)d_in[0];
    const float* stem_w  = (const float*)d_in[1];
    const float* stem_b  = (const float*)d_in[2];
    const float* ln_g    = (const float*)d_in[3];
    const float* ln_b    = (const float*)d_in[4];
    const float* in_w    = (const float*)d_in[5];
    const float* conv_w  = (const float*)d_in[6];
    const float* conv_b  = (const float*)d_in[7];
    const float* xw      = (const float*)d_in[8];
    const float* dt_w    = (const float*)d_in[9];
    const float* dt_b    = (const float*)d_in[10];
    const float* A_log   = (const float*)d_in[11];
    const float* Dv      = (const float*)d_in[12];
    const float* out_w   = (const float*)d_in[13];
    const float* head_w  = (const float*)d_in[14];
    const float* head_b  = (const float*)d_in[15];
    float* out = (float*)d_out;

    float* ws     = (float*)d_ws;
    float* h      = ws;
    float* zbuf   = h    + (size_t)BB * LSEQ * DMODEL;
    float* dbuf   = zbuf + (size_t)BB * LSEQ * DINNER;
    float* Cmb    = dbuf + (size_t)BB * LSEQ * DINNER;
    float* ybuf   = Cmb  + (size_t)BB * LSEQ * DSTATE;
    float* Pb     = ybuf + (size_t)BB * LSEQ * DINNER;
    float* hFb    = Pb   + (size_t)BB * NCH * DINNER * DSTATE;
    float* wend   = hFb  + (size_t)BB * NCH * DINNER * DSTATE;
    unsigned short* Wib = (unsigned short*)wend;
    unsigned short* Wob = Wib + (size_t)NLAYERS * 65536;
    unsigned short* Wxb = Wob + (size_t)NLAYERS * 32768;
    float* hinb = Pb;   // alias: combine overwrites P with hin (safe)

    k_cvt_in<<<(NLAYERS * 65536 + 255) / 256, 256, 0, stream>>>(in_w, Wib);
    k_cvt_out<<<(NLAYERS * 32768 + 255) / 256, 256, 0, stream>>>(out_w, Wob);
    k_cvt_xw<<<(NLAYERS * 12288 + 255) / 256, 256, 0, stream>>>(xw, Wxb);
    k_stem<<<(BB * LSEQ * DMODEL + 255) / 256, 256, 0, stream>>>(x, stem_w, stem_b, h);

    dim3 g_scan(NCH, BB);
    dim3 g_c(LSEQ / 16, BB);
    for (int ly = 0; ly < NLAYERS; ly++) {
        k_fused_a<<<g_scan, 256, 0, stream>>>(
            h, ln_g + ly * DMODEL, ln_b + ly * DMODEL,
            Wib + (size_t)ly * 65536, Wxb + (size_t)ly * 12288,
            conv_w + (size_t)ly * DINNER * 4, conv_b + (size_t)ly * DINNER,
            dt_w + (size_t)ly * DINNER * 8, dt_b + (size_t)ly * DINNER,
            A_log + (size_t)ly * DINNER * DSTATE, Dv + (size_t)ly * DINNER,
            zbuf, dbuf, Cmb, ybuf, Pb, hFb);
        k_combine<<<(BB * DINNER * DSTATE + 255) / 256, 256, 0, stream>>>(Pb, hFb, hinb);
        k_layer_c<<<g_c, 256, 0, stream>>>(
            dbuf, Cmb, A_log + (size_t)ly * DINNER * DSTATE, hinb,
            ybuf, zbuf, Wob + (size_t)ly * 32768, h);
    }
    k_head<<<BB, 256, 0, stream>>>(h, head_w, head_b, out);
}